// Round 13
// baseline (605.762 us; speedup 1.0000x reference)
//
#include <hip/hip_runtime.h>

// ---------------- problem constants ----------------
#define N_NODES 32768
#define E_EDGES 524288
#define F_IN    215
#define H_DIM   256
#define T_TYPES 8
#define L_LAYERS 3
#define B_GRAPHS 32
#define MAXN_   1024
#define NT_BINS (N_NODES * T_TYPES)   // 262144

typedef float  f32x4  __attribute__((ext_vector_type(4)));
typedef float  f32x2  __attribute__((ext_vector_type(2)));
typedef __bf16 bf16x8 __attribute__((ext_vector_type(8)));

__device__ __forceinline__ unsigned short f2bf(float f) {
  union { float f; unsigned u; } v; v.f = f;
  unsigned r = v.u + 0x7fffu + ((v.u >> 16) & 1u);
  return (unsigned short)(r >> 16);
}
__device__ __forceinline__ float bf2f(unsigned short h) {
  union { unsigned u; float f; } v; v.u = ((unsigned)h) << 16;
  return v.f;
}
__device__ __forceinline__ float bflo(unsigned u) { union { unsigned x; float f; } v; v.x = u << 16; return v.f; }
__device__ __forceinline__ float bfhi(unsigned u) { union { unsigned x; float f; } v; v.x = u & 0xffff0000u; return v.f; }

// bf16 pair (packed in u32) -> float2; adds on f32x2 compile to v_pk_add_f32
// (two independent IEEE f32 adds -> bit-identical to scalar v_add_f32).
__device__ __forceinline__ f32x2 bf2x(unsigned u) {
  union { unsigned x[2]; f32x2 f; } v;
  v.x[0] = u << 16;
  v.x[1] = u & 0xffff0000u;
  return v.f;
}

typedef const __attribute__((address_space(1))) unsigned int* gas_ptr;
typedef __attribute__((address_space(3))) unsigned int* las_ptr;
__device__ __forceinline__ void gload_lds16(const unsigned short* g, unsigned short* l) {
  __builtin_amdgcn_global_load_lds((gas_ptr)g, (las_ptr)l, 16, 0, 0);
}

// packed gather accumulate: 8 x v_pk_add_f32 + 16 bit-ops (was 16 add + 16 bit)
__device__ __forceinline__ void acc16p(f32x2* a, const uint4 v, const uint4 w) {
  a[0] += bf2x(v.x); a[1] += bf2x(v.y);
  a[2] += bf2x(v.z); a[3] += bf2x(v.w);
  a[4] += bf2x(w.x); a[5] += bf2x(w.y);
  a[6] += bf2x(w.z); a[7] += bf2x(w.w);
}

// ---------------- ws layout (bytes) ----------------
static constexpr size_t OFF_BIG     = 0;            // 134217728
static constexpr size_t REL_CURSOR  = 1048576;
static constexpr size_t REL_BSUM    = 2097152;
static constexpr size_t REL_WPPAD   = 33554432;
static constexpr size_t REL_HALT    = 50331648;
static constexpr size_t REL_OFFS    = 100663296;
static constexpr size_t REL_SORTED  = 104857600;
static constexpr size_t OFF_H_B     = 134217728;    // 16777216   h bf16 (N,H)
static constexpr size_t OFF_M_B     = 150994944;    // 16777216   m bf16 (N,H)
static constexpr size_t OFF_WMB     = 167772160;    // 3145728    Wm bf16 (L,T,H,H) natural
static constexpr size_t OFF_WIH     = 170917888;    // 1179648    Wih bf16
static constexpr size_t OFF_WHH     = 172097536;    // 1179648    Whh bf16
static constexpr size_t WS_REQUIRED = 173277184;    // < 175.9 MB proven safe

// ---------------- edge preprocessing: counting sort by key=(dst*8+type) ----------------
__global__ void hist_kernel(const int* __restrict__ dst, const int* __restrict__ et,
                            int* __restrict__ cnt) {
  int e = blockIdx.x * 256 + threadIdx.x;
  atomicAdd(&cnt[dst[e] * T_TYPES + et[e]], 1);
}

__global__ __launch_bounds__(1024) void scan1(const int* __restrict__ cnt,
                                              int* __restrict__ offs,
                                              int* __restrict__ bsum) {
  __shared__ int wsum[16];
  const int t = threadIdx.x, lane = t & 63, wid = t >> 6;
  const int idx = blockIdx.x * 1024 + t;
  const int v = cnt[idx];
  int x = v;
  #pragma unroll
  for (int off = 1; off < 64; off <<= 1) {
    int u = __shfl_up(x, off, 64);
    if (lane >= off) x += u;
  }
  if (lane == 63) wsum[wid] = x;
  __syncthreads();
  int wbase = 0;
  for (int i = 0; i < wid; ++i) wbase += wsum[i];
  offs[idx] = wbase + x - v;
  if (t == 1023) bsum[blockIdx.x] = wbase + x;
}

__global__ __launch_bounds__(256) void scan2(int* __restrict__ bsum) {
  __shared__ int wsum[4];
  const int t = threadIdx.x, lane = t & 63, wid = t >> 6;
  const int v = bsum[t];
  int x = v;
  #pragma unroll
  for (int off = 1; off < 64; off <<= 1) {
    int u = __shfl_up(x, off, 64);
    if (lane >= off) x += u;
  }
  if (lane == 63) wsum[wid] = x;
  __syncthreads();
  int wbase = 0;
  for (int i = 0; i < wid; ++i) wbase += wsum[i];
  __syncthreads();
  bsum[t] = wbase + x - v;
}

__global__ __launch_bounds__(1024) void scan3(int* __restrict__ offs,
                                              const int* __restrict__ bsum,
                                              int* __restrict__ cursor) {
  const int idx = blockIdx.x * 1024 + threadIdx.x;
  const int o = offs[idx] + bsum[blockIdx.x];
  offs[idx] = o;
  cursor[idx] = o;
  if (idx == 0) offs[NT_BINS] = E_EDGES;
}

__global__ void reorder_kernel(const int* __restrict__ src, const int* __restrict__ dst,
                               const int* __restrict__ et, int* __restrict__ cursor,
                               unsigned short* __restrict__ sorted) {
  int e = blockIdx.x * 256 + threadIdx.x;
  int key = dst[e] * T_TYPES + et[e];
  int p = atomicAdd(&cursor[key], 1);
  sorted[p] = (unsigned short)src[e];
}

// ---------------- conversions (G13: 8 elems/thread, vector stores) ----------
__global__ void cvt_weights8(const float* __restrict__ a, const float* __restrict__ b,
                             const float* __restrict__ c,
                             unsigned short* __restrict__ oa, unsigned short* __restrict__ ob,
                             unsigned short* __restrict__ oc,
                             int na, int nb, int nc) {
  const int i = (blockIdx.x * 256 + threadIdx.x) * 8;
  const float* s; unsigned short* d; int off;
  if (i < na) { s = a; d = oa; off = i; }
  else {
    const int j = i - na;
    if (j < nb) { s = b; d = ob; off = j; }
    else {
      const int k = j - nb;
      if (k >= nc) return;
      s = c; d = oc; off = k;
    }
  }
  // na/nb multiples of 8 -> off multiple of 8 -> 32B-aligned float4 loads
  const float4 v0 = *(const float4*)(s + off);
  const float4 v1 = *(const float4*)(s + off + 4);
  union { unsigned short us[8]; uint4 q; } o;
  o.us[0] = f2bf(v0.x); o.us[1] = f2bf(v0.y); o.us[2] = f2bf(v0.z); o.us[3] = f2bf(v0.w);
  o.us[4] = f2bf(v1.x); o.us[5] = f2bf(v1.y); o.us[6] = f2bf(v1.z); o.us[7] = f2bf(v1.w);
  *(uint4*)(d + off) = o.q;
}

__global__ void pad_cvt8(const float* __restrict__ in, unsigned short* __restrict__ out,
                         int rows, int cin) {
  const int i = (blockIdx.x * 256 + threadIdx.x) * 8;
  if (i >= rows * 256) return;
  const int r = i >> 8, c0 = i & 255;
  union { unsigned short us[8]; uint4 q; } o;
  #pragma unroll
  for (int j = 0; j < 8; ++j) {
    const int c = c0 + j;
    o.us[j] = (c < cin) ? f2bf(in[(size_t)r * cin + c]) : (unsigned short)0;
  }
  *(uint4*)(out + i) = o.q;   // i multiple of 8 shorts -> 16B aligned
}

// ---------------- GEMM: C(N x M) = A(N x K) @ W(M x K)^T + bias (input proj) ------
// 2-phase pipelined + XOR slot swizzle (unchanged, verified).
__global__ __launch_bounds__(256, 2) void gemm_bt(
    const unsigned short* __restrict__ A,
    const unsigned short* __restrict__ W,
    const float* __restrict__ bias,
    unsigned short* __restrict__ C,
    int M, int K) {
  __shared__ unsigned short As[2][128 * 32];
  __shared__ unsigned short Bs[2][128 * 32];
  const int tid = threadIdx.x;
  const int lane = tid & 63;
  const int wv = tid >> 6;
  const int lrow = lane & 15;
  const int lquad = lane >> 4;
  const int bm0 = blockIdx.x * 128;
  const int bn0 = blockIdx.y * 128;
  const int srow = wv * 16 + (lane >> 2);
  const int sslot = lane & 3;
  const int scol = sslot * 8;
  const int ssw = (sslot ^ ((lane >> 3) & 3)) * 8;   // swizzled global col
  const int rsw = (lquad ^ ((lane >> 1) & 3)) * 8;   // swizzled LDS read col

  f32x4 acc[2][8] = {};

#define GBT_STAGE(b, kt)                                                              \
  { _Pragma("unroll") for (int i = 0; i < 2; ++i) {                                   \
      const int row = srow + i * 64;                                                  \
      gload_lds16(A + (size_t)(bm0 + row) * K + (kt) + ssw, &As[b][row * 32 + scol]); \
      gload_lds16(W + (size_t)(bn0 + row) * K + (kt) + ssw, &Bs[b][row * 32 + scol]); \
    } }

  GBT_STAGE(0, 0);
  __syncthreads();
  const int nk = K >> 5;
  for (int ki = 0; ki < nk; ++ki) {
    const int cur = ki & 1;
    if (ki + 1 < nk) GBT_STAGE(cur ^ 1, (ki + 1) * 32);
    bf16x8 af[2], bfr[8];
    #pragma unroll
    for (int mt = 0; mt < 2; ++mt)
      af[mt] = *(const bf16x8*)(&As[cur][(wv * 32 + mt * 16 + lrow) * 32 + rsw]);
    #pragma unroll
    for (int nt = 0; nt < 8; ++nt)
      bfr[nt] = *(const bf16x8*)(&Bs[cur][(nt * 16 + lrow) * 32 + rsw]);
    #pragma unroll
    for (int mt = 0; mt < 2; ++mt)
      #pragma unroll
      for (int nt = 0; nt < 8; ++nt)
        acc[mt][nt] = __builtin_amdgcn_mfma_f32_16x16x32_bf16(af[mt], bfr[nt], acc[mt][nt], 0, 0, 0);
    __syncthreads();
  }
#undef GBT_STAGE

  #pragma unroll
  for (int mt = 0; mt < 2; ++mt) {
    #pragma unroll
    for (int r = 0; r < 4; ++r) {
      const int grow = bm0 + wv * 32 + mt * 16 + lquad * 4 + r;
      #pragma unroll
      for (int nt = 0; nt < 8; ++nt) {
        const int gcol = bn0 + nt * 16 + lrow;
        float v = acc[mt][nt][r] + (bias ? bias[gcol] : 0.f);
        C[(size_t)grow * M + gcol] = f2bf(v);
      }
    }
  }
}

// ---------------- fused message GEMM: counted-vmcnt phase B, 2x4 wave tiles --
// (round-10 verified 81.3us; pk-add gather r11. FROZEN.)
__global__ __launch_bounds__(512, 4) void msg_gemm(
    const int* __restrict__ offs, const unsigned short* __restrict__ sorted,
    const unsigned short* __restrict__ hb, const unsigned short* __restrict__ Wt_l,
    const float* __restrict__ bm_l, unsigned short* __restrict__ m) {
  constexpr int CH = 2568;                    // Ss chunk stride (shorts)
  __shared__ unsigned short Ss[8 * CH];       // 41.1 KB
  __shared__ unsigned short Bs[2][256 * 32];  // 32 KB ping-pong
  __shared__ unsigned short idxS[2048];       // 4 KB edge indices
  __shared__ int offsS[516];                  // 2 KB offs segment
  const int tid = threadIdx.x;
  const int lane = tid & 63;
  const int wv = tid >> 6;            // 0..7
  const int lrow = lane & 15;
  const int lquad = lane >> 4;
  const int wr2 = wv & 1;             // row half: rows wr2*32 .. +31
  const int wc4 = wv >> 1;            // col quarter: cols wc4*64 .. +63
  const int bm0 = blockIdx.x * 64;
  const int gg = wv * 4 + lquad;      // gather group 0..31
  const int brow = tid >> 2;          // 0..127 (Bs staging row)
  const int bslot = tid & 3;
  const int bcol = bslot * 8;
  const int bsw = (bslot ^ ((tid >> 3) & 3)) * 8;    // swizzled global col (stage)
  const int rsw = (lquad ^ ((lane >> 1) & 3)) * 8;   // swizzled LDS read col

#define MSG_STAGE(W_, kc_, b_)                                                         \
  { gload_lds16((W_) + (size_t)brow * 256 + (kc_) * 32 + bsw, &Bs[b_][brow * 32 + bcol]); \
    gload_lds16((W_) + (size_t)(brow + 128) * 256 + (kc_) * 32 + bsw,                  \
                &Bs[b_][(brow + 128) * 32 + bcol]); }

  // ---- stage offs + edge-index segments; prefetch (t0,kc0) weights ----
  MSG_STAGE(Wt_l, 0, 0);
  const int gseg0 = offs[bm0 * 8];
  const int gseg1 = offs[bm0 * 8 + 512];
  const int seg = gseg1 - gseg0;
  for (int i = tid; i < 513; i += 512) offsS[i] = offs[bm0 * 8 + i];
  const int segc = seg < 2048 ? seg : 2048;
  for (int i = tid; i < segc; i += 512) idxS[i] = sorted[gseg0 + i];
  const bool useLds = (seg <= 2048);
  const unsigned short* ip = useLds ? (const unsigned short*)idxS : (sorted + gseg0);
  __syncthreads();

  f32x4 acc[2][4] = {};   // [row-tile mt][col-tile nt]
  int buf = 0;

  for (int t = 0; t < T_TYPES; ++t) {
    // ---- phase A: build S_t (64 x 256) in LDS (packed-add gather) ----
    #pragma unroll
    for (int step = 0; step < 2; ++step) {
      const int dloc = gg + step * 32;
      const int beg = offsS[dloc * 8 + t] - gseg0;
      const int end = offsS[dloc * 8 + t + 1] - gseg0;
      f32x2 a[8];
      #pragma unroll
      for (int j = 0; j < 8; ++j) a[j] = (f32x2){0.f, 0.f};
      int e = beg;
      if (e + 2 <= end) {
        int s0 = ip[e], s1 = ip[e + 1];
        const unsigned short* h0 = hb + (size_t)s0 * H_DIM + lrow * 16;
        const unsigned short* h1 = hb + (size_t)s1 * H_DIM + lrow * 16;
        uint4 pv0 = *(const uint4*)h0, pw0 = *(const uint4*)(h0 + 8);
        uint4 pv1 = *(const uint4*)h1, pw1 = *(const uint4*)(h1 + 8);
        e += 2;
        for (; e + 2 <= end; e += 2) {
          const int n0 = ip[e], n1 = ip[e + 1];
          const unsigned short* g0 = hb + (size_t)n0 * H_DIM + lrow * 16;
          const unsigned short* g1 = hb + (size_t)n1 * H_DIM + lrow * 16;
          const uint4 nv0 = *(const uint4*)g0, nw0 = *(const uint4*)(g0 + 8);
          const uint4 nv1 = *(const uint4*)g1, nw1 = *(const uint4*)(g1 + 8);
          acc16p(a, pv0, pw0);
          acc16p(a, pv1, pw1);
          pv0 = nv0; pw0 = nw0; pv1 = nv1; pw1 = nw1;
        }
        acc16p(a, pv0, pw0);
        acc16p(a, pv1, pw1);
      }
      if (e < end) {
        const int s0 = ip[e];
        const unsigned short* h0 = hb + (size_t)s0 * H_DIM + lrow * 16;
        acc16p(a, *(const uint4*)h0, *(const uint4*)(h0 + 8));
      }
      union { unsigned short us[16]; uint4 q[2]; } ob;
      #pragma unroll
      for (int j = 0; j < 8; ++j) {
        ob.us[2 * j]     = f2bf(a[j][0]);
        ob.us[2 * j + 1] = f2bf(a[j][1]);
      }
      uint4* p = (uint4*)&Ss[(lrow >> 1) * CH + dloc * 40 + (lrow & 1) * 16];
      p[0] = ob.q[0];
      p[1] = ob.q[1];
    }
    __syncthreads();   // full drain: Ss ds_writes visible; Bs[buf] (kc0) drained
    const unsigned short* Wt  = Wt_l + (size_t)t * 65536;
    const unsigned short* Wtn = Wt_l + (size_t)(t + 1) * 65536;  // deref'd only t<7
    // ---- phase B: acc += S_t @ Wm[t]^T ----
    for (int kc = 0; kc < 8; ++kc) {
      if (kc < 7) {
        MSG_STAGE(Wt, kc + 1, buf ^ 1);            // prefetch kc+1
      } else if (t < 7) {
        MSG_STAGE(Wtn, 0, buf ^ 1);                // cross-type prefetch kc0
      }
      if (t == 7 && kc == 7) {
        asm volatile("s_waitcnt vmcnt(0)" ::: "memory");
      } else {
        asm volatile("s_waitcnt vmcnt(2)" ::: "memory");  // drain kc's tile only
      }
      __builtin_amdgcn_s_barrier();                // all waves' kc tile in LDS
      __builtin_amdgcn_sched_barrier(0);
      bf16x8 af[2], bfr[4];
      #pragma unroll
      for (int mt = 0; mt < 2; ++mt)
        af[mt] = *(const bf16x8*)(&Ss[kc * CH + (wr2 * 32 + mt * 16 + lrow) * 40 + lquad * 8]);
      #pragma unroll
      for (int nt = 0; nt < 4; ++nt)
        bfr[nt] = *(const bf16x8*)(&Bs[buf][((wc4 * 4 + nt) * 16 + lrow) * 32 + rsw]);
      #pragma unroll
      for (int mt = 0; mt < 2; ++mt)
        #pragma unroll
        for (int nt = 0; nt < 4; ++nt)
          acc[mt][nt] = __builtin_amdgcn_mfma_f32_16x16x32_bf16(af[mt], bfr[nt], acc[mt][nt], 0, 0, 0);
      buf ^= 1;
      __builtin_amdgcn_s_barrier();                // reads done before overwrite
      __builtin_amdgcn_sched_barrier(0);
    }
  }
#undef MSG_STAGE

  // ---- epilogue: m = acc + sum_t cnt[dst,t]*bm[t,:]; cnt from offsS deltas ----
  #pragma unroll
  for (int mt = 0; mt < 2; ++mt) {
    float cnt[4][8];
    #pragma unroll
    for (int r = 0; r < 4; ++r) {
      const int dl = wr2 * 32 + mt * 16 + lquad * 4 + r;
      #pragma unroll
      for (int t = 0; t < 8; ++t)
        cnt[r][t] = (float)(offsS[dl * 8 + t + 1] - offsS[dl * 8 + t]);
    }
    #pragma unroll
    for (int nt = 0; nt < 4; ++nt) {
      const int gcol = wc4 * 64 + nt * 16 + lrow;
      float bmv[8];
      #pragma unroll
      for (int t = 0; t < 8; ++t) bmv[t] = bm_l[t * H_DIM + gcol];
      #pragma unroll
      for (int r = 0; r < 4; ++r) {
        const int grow = bm0 + wr2 * 32 + mt * 16 + lquad * 4 + r;
        float v = acc[mt][nt][r];
        #pragma unroll
        for (int t = 0; t < 8; ++t) v += cnt[r][t] * bmv[t];
        m[(size_t)grow * H_DIM + gcol] = f2bf(v);
      }
    }
  }
}

// ---------------- fused GRU: 4-acc gate fusion + bfr double-buffer ----------
// r12's gate fusion (acc 6->4 tiles, 64 AGPR) freed the budget to reinstate
// the r1/r2-verified bfr dbuf: loads for ki+1 issued BEFORE ki's MFMAs, so
// the ~200-300cy L2 latency of the 6 weight loads hides under MFMA+ds_read
// instead of being eaten serially at the barrier (r9's single-buffer tail).
// Regs: ~80 arch + 24 bfr + 64 acc = 168 <= 170 cap at (256,3) -> 3 waves/
// SIMD. Fully unrolled so bfr[cur] is static (rule #20). Spill tripwire:
// WRITE_SIZE must stay 16384 (r4 signature) — if it blows up, revert dbuf.
__global__ __launch_bounds__(256, 3) void gru_fused(
    const unsigned short* __restrict__ mB,
    const unsigned short* __restrict__ hin,
    const unsigned short* __restrict__ wih_l,
    const unsigned short* __restrict__ whh_l,
    const float* __restrict__ bih_l,
    const float* __restrict__ bhh_l,
    unsigned short* __restrict__ hout) {
  __shared__ unsigned short Am[2][64 * 32];   // 8 KB dbuf
  __shared__ unsigned short Ah[2][64 * 32];   // 8 KB dbuf
  const int tid = threadIdx.x;
  const int lane = tid & 63;
  const int wv = tid >> 6;
  const int lrow = lane & 15;
  const int lquad = lane >> 4;
  const int n0 = blockIdx.x * 64;
  const int c0 = blockIdx.y * 64;
  const int arow = tid >> 2;
  const int sslot = tid & 3;
  const int ssw = (sslot ^ ((tid >> 3) & 3)) * 8;    // swizzled global col (stage)
  const int rsw = (lquad ^ ((lane >> 1) & 3)) * 8;   // swizzled LDS read col
  const int wr = c0 + wv * 16 + lrow;

  // acc tiles: 0 = i_r+h_r, 1 = i_z+h_z, 2 = i_n, 3 = h_n
  f32x4 acc[4][4] = {};
  bf16x8 bfr[2][6];

#define GRU_LOADB(bi, kt)                                                                      \
  { _Pragma("unroll") for (int g = 0; g < 3; ++g) {                                            \
      bfr[bi][g]     = *(const bf16x8*)(wih_l + (size_t)(g * 256 + wr) * 256 + (kt) + lquad * 8); \
      bfr[bi][g + 3] = *(const bf16x8*)(whh_l + (size_t)(g * 256 + wr) * 256 + (kt) + lquad * 8); \
    } }
#define GRU_STAGE(b, kt)                                                                       \
  { gload_lds16(mB  + (size_t)(n0 + arow) * 256 + (kt) + ssw, &Am[b][arow * 32 + sslot * 8]);  \
    gload_lds16(hin + (size_t)(n0 + arow) * 256 + (kt) + ssw, &Ah[b][arow * 32 + sslot * 8]); }

  GRU_LOADB(0, 0);
  GRU_STAGE(0, 0);
  __syncthreads();

  #pragma unroll
  for (int ki = 0; ki < 8; ++ki) {
    const int cur = ki & 1;
    if (ki < 7) {
      GRU_LOADB(cur ^ 1, (ki + 1) * 32);   // VMEM->VGPR prefetch (issued first)
      GRU_STAGE(cur ^ 1, (ki + 1) * 32);   // VMEM->LDS prefetch
    }
    #pragma unroll
    for (int mt = 0; mt < 4; ++mt) {
      const bf16x8 am = *(const bf16x8*)(&Am[cur][(mt * 16 + lrow) * 32 + rsw]);
      const bf16x8 ah = *(const bf16x8*)(&Ah[cur][(mt * 16 + lrow) * 32 + rsw]);
      // r-gate sum: m@W_ir + h@W_hr into one tile
      acc[0][mt] = __builtin_amdgcn_mfma_f32_16x16x32_bf16(am, bfr[cur][0], acc[0][mt], 0, 0, 0);
      acc[0][mt] = __builtin_amdgcn_mfma_f32_16x16x32_bf16(ah, bfr[cur][3], acc[0][mt], 0, 0, 0);
      // z-gate sum
      acc[1][mt] = __builtin_amdgcn_mfma_f32_16x16x32_bf16(am, bfr[cur][1], acc[1][mt], 0, 0, 0);
      acc[1][mt] = __builtin_amdgcn_mfma_f32_16x16x32_bf16(ah, bfr[cur][4], acc[1][mt], 0, 0, 0);
      // n-gate halves (kept separate for r * h_n)
      acc[2][mt] = __builtin_amdgcn_mfma_f32_16x16x32_bf16(am, bfr[cur][2], acc[2][mt], 0, 0, 0);
      acc[3][mt] = __builtin_amdgcn_mfma_f32_16x16x32_bf16(ah, bfr[cur][5], acc[3][mt], 0, 0, 0);
    }
    __syncthreads();   // drains prefetch (vmcnt(0)) + protects dbuf reuse
  }
#undef GRU_LOADB
#undef GRU_STAGE

  const int c = c0 + wv * 16 + lrow;
  const float b_ir = bih_l[c], b_iz = bih_l[256 + c], b_in = bih_l[512 + c];
  const float b_hr = bhh_l[c], b_hz = bhh_l[256 + c], b_hn = bhh_l[512 + c];
  #pragma unroll
  for (int mt = 0; mt < 4; ++mt) {
    #pragma unroll
    for (int r = 0; r < 4; ++r) {
      const int node = n0 + mt * 16 + lquad * 4 + r;
      const float s_r = acc[0][mt][r] + b_ir + b_hr;   // i_r + h_r (+biases)
      const float s_z = acc[1][mt][r] + b_iz + b_hz;
      const float i_n = acc[2][mt][r] + b_in;
      const float h_n = acc[3][mt][r] + b_hn;
      const float rr = 1.f / (1.f + __expf(-s_r));
      const float zz = 1.f / (1.f + __expf(-s_z));
      const float nn = tanhf(i_n + rr * h_n);
      const float hp = bf2f(hin[(size_t)node * 256 + c]);
      hout[(size_t)node * 256 + c] = f2bf((1.f - zz) * nn + zz * hp);
    }
  }
}

// ---------------- readout ----------------
__global__ __launch_bounds__(256) void readout_partial(const unsigned short* __restrict__ hb,
                                                       float* __restrict__ part) {
  const int b = blockIdx.x >> 3;
  const int ch = blockIdx.x & 7;
  const int c = threadIdx.x;
  const unsigned short* base = hb + ((size_t)b * MAXN_ + ch * 128) * H_DIM + c;
  float s = 0.f;
  #pragma unroll 4
  for (int i = 0; i < 128; ++i) s += bf2f(base[(size_t)i * H_DIM]);
  part[(size_t)blockIdx.x * H_DIM + c] = s;
}

__global__ __launch_bounds__(256) void readout_final(const float* __restrict__ part,
                                                     float* __restrict__ out) {
  const int b = blockIdx.x;
  const int c = threadIdx.x;
  float s = 0.f;
  #pragma unroll
  for (int i = 0; i < 8; ++i) s += part[((size_t)b * 8 + i) * H_DIM + c];
  out[b * H_DIM + c] = s;
}

// ---------------- launch ----------------
extern "C" void kernel_launch(void* const* d_in, const int* in_sizes, int n_in,
                              void* d_out, int out_size, void* d_ws, size_t ws_size,
                              hipStream_t stream) {
  if (ws_size < WS_REQUIRED) return;  // diagnostic no-op guard

  const float* X   = (const float*)d_in[0];
  const int*   ei  = (const int*)d_in[1];
  const int*   et  = (const int*)d_in[2];
  const float* Wp  = (const float*)d_in[3];
  const float* bp  = (const float*)d_in[4];
  const float* Wm  = (const float*)d_in[5];
  const float* bm  = (const float*)d_in[6];
  const float* Wih = (const float*)d_in[7];
  const float* Whh = (const float*)d_in[8];
  const float* bih = (const float*)d_in[9];
  const float* bhh = (const float*)d_in[10];
  float* out = (float*)d_out;
  char* ws = (char*)d_ws;

  // BIG aliases (stream-ordered liveness)
  int*            counts = (int*)(ws + OFF_BIG);
  int*            cursor = (int*)(ws + OFF_BIG + REL_CURSOR);
  int*            bsum   = (int*)(ws + OFF_BIG + REL_BSUM);
  unsigned short* xpad   = (unsigned short*)(ws + OFF_BIG);
  unsigned short* wppad  = (unsigned short*)(ws + OFF_BIG + REL_WPPAD);
  unsigned short* h_alt  = (unsigned short*)(ws + OFF_BIG + REL_HALT);
  float*          part   = (float*)(ws + OFF_BIG);
  int*            offs   = (int*)(ws + OFF_BIG + REL_OFFS);
  unsigned short* sorted = (unsigned short*)(ws + OFF_BIG + REL_SORTED);
  // persistent
  unsigned short* h_b    = (unsigned short*)(ws + OFF_H_B);
  unsigned short* m_b    = (unsigned short*)(ws + OFF_M_B);
  unsigned short* wmb    = (unsigned short*)(ws + OFF_WMB);
  unsigned short* wih_b  = (unsigned short*)(ws + OFF_WIH);
  unsigned short* whh_b  = (unsigned short*)(ws + OFF_WHH);

  const int* src = ei;
  const int* dst = ei + E_EDGES;

  // ---- counting sort of edges by (dst*8 + type), once ----
  hipMemsetAsync(counts, 0, NT_BINS * sizeof(int), stream);
  hist_kernel<<<E_EDGES / 256, 256, 0, stream>>>(dst, et, counts);
  scan1<<<NT_BINS / 1024, 1024, 0, stream>>>(counts, offs, bsum);
  scan2<<<1, 256, 0, stream>>>(bsum);
  scan3<<<NT_BINS / 1024, 1024, 0, stream>>>(offs, bsum, cursor);
  reorder_kernel<<<E_EDGES / 256, 256, 0, stream>>>(src, dst, et, cursor, sorted);

  // ---- weight/input conversion to bf16 (vectorized 8/thread) ----
  pad_cvt8<<<(N_NODES * 256) / 2048, 256, 0, stream>>>(X, xpad, N_NODES, F_IN);
  pad_cvt8<<<(256 * 256) / 2048, 256, 0, stream>>>(Wp, wppad, 256, F_IN);
  {
    const int na = L_LAYERS * T_TYPES * H_DIM * H_DIM;   // 1572864
    const int nb = L_LAYERS * 3 * H_DIM * H_DIM;         // 589824
    const int nc = nb;
    cvt_weights8<<<((na + nb + nc) / 8 + 255) / 256, 256, 0, stream>>>(
        Wm, Wih, Whh, wmb, wih_b, whh_b, na, nb, nc);
  }

  // ---- input projection: h = X @ Wp^T + bp ----
  gemm_bt<<<dim3(N_NODES / 128, 2), 256, 0, stream>>>(xpad, wppad, bp, h_b, H_DIM, 256);

  for (int l = 0; l < L_LAYERS; ++l) {
    const unsigned short* wm_l  = wmb + (size_t)l * T_TYPES * H_DIM * H_DIM;
    const unsigned short* wih_l = wih_b + (size_t)l * 3 * H_DIM * H_DIM;
    const unsigned short* whh_l = whh_b + (size_t)l * 3 * H_DIM * H_DIM;
    const float* bm_l  = bm + (size_t)l * T_TYPES * H_DIM;
    const float* bih_l = bih + (size_t)l * 3 * H_DIM;
    const float* bhh_l = bhh + (size_t)l * 3 * H_DIM;

    unsigned short* h_cur = (l & 1) ? h_alt : h_b;
    unsigned short* h_nxt = (l & 1) ? h_b : h_alt;

    // fused: m = (scatter-sum_t h) @ Wm^T + cnt-weighted bm  (S stays in LDS)
    msg_gemm<<<N_NODES / 64, 512, 0, stream>>>(offs, sorted, h_cur, wm_l, bm_l, m_b);
    // fused: h_nxt = GRU(m, h_cur)  (gi/gh stay in registers)
    gru_fused<<<dim3(N_NODES / 64, 4), 256, 0, stream>>>(
        m_b, h_cur, wih_l, whh_l, bih_l, bhh_l, h_nxt);
  }

  // final h is in h_alt (l=2 writes h_alt); part at BIG+0 is disjoint
  readout_partial<<<B_GRAPHS * 8, 256, 0, stream>>>(h_alt, part);
  readout_final<<<B_GRAPHS, 256, 0, stream>>>(part, out);

  (void)in_sizes; (void)n_in; (void)out_size;
}

// Round 14
// 593.124 us; speedup vs baseline: 1.0213x; 1.0213x over previous
//
#include <hip/hip_runtime.h>

// ---------------- problem constants ----------------
#define N_NODES 32768
#define E_EDGES 524288
#define F_IN    215
#define H_DIM   256
#define T_TYPES 8
#define L_LAYERS 3
#define B_GRAPHS 32
#define MAXN_   1024
#define NT_BINS (N_NODES * T_TYPES)   // 262144

typedef float  f32x4  __attribute__((ext_vector_type(4)));
typedef float  f32x2  __attribute__((ext_vector_type(2)));
typedef __bf16 bf16x8 __attribute__((ext_vector_type(8)));

__device__ __forceinline__ unsigned short f2bf(float f) {
  union { float f; unsigned u; } v; v.f = f;
  unsigned r = v.u + 0x7fffu + ((v.u >> 16) & 1u);
  return (unsigned short)(r >> 16);
}
__device__ __forceinline__ float bf2f(unsigned short h) {
  union { unsigned u; float f; } v; v.u = ((unsigned)h) << 16;
  return v.f;
}
__device__ __forceinline__ float bflo(unsigned u) { union { unsigned x; float f; } v; v.x = u << 16; return v.f; }
__device__ __forceinline__ float bfhi(unsigned u) { union { unsigned x; float f; } v; v.x = u & 0xffff0000u; return v.f; }

// bf16 pair (packed in u32) -> float2; adds on f32x2 compile to v_pk_add_f32
// (two independent IEEE f32 adds -> bit-identical to scalar v_add_f32).
__device__ __forceinline__ f32x2 bf2x(unsigned u) {
  union { unsigned x[2]; f32x2 f; } v;
  v.x[0] = u << 16;
  v.x[1] = u & 0xffff0000u;
  return v.f;
}

typedef const __attribute__((address_space(1))) unsigned int* gas_ptr;
typedef __attribute__((address_space(3))) unsigned int* las_ptr;
__device__ __forceinline__ void gload_lds16(const unsigned short* g, unsigned short* l) {
  __builtin_amdgcn_global_load_lds((gas_ptr)g, (las_ptr)l, 16, 0, 0);
}

// packed gather accumulate: 8 x v_pk_add_f32 + 16 bit-ops (was 16 add + 16 bit)
__device__ __forceinline__ void acc16p(f32x2* a, const uint4 v, const uint4 w) {
  a[0] += bf2x(v.x); a[1] += bf2x(v.y);
  a[2] += bf2x(v.z); a[3] += bf2x(v.w);
  a[4] += bf2x(w.x); a[5] += bf2x(w.y);
  a[6] += bf2x(w.z); a[7] += bf2x(w.w);
}

// ---------------- ws layout (bytes) ----------------
static constexpr size_t OFF_BIG     = 0;            // 134217728
static constexpr size_t REL_CURSOR  = 1048576;
static constexpr size_t REL_BSUM    = 2097152;
static constexpr size_t REL_WPPAD   = 33554432;
static constexpr size_t REL_HALT    = 50331648;
static constexpr size_t REL_OFFS    = 100663296;
static constexpr size_t REL_SORTED  = 104857600;
static constexpr size_t OFF_H_B     = 134217728;    // 16777216   h bf16 (N,H)
static constexpr size_t OFF_M_B     = 150994944;    // 16777216   m bf16 (N,H)
static constexpr size_t OFF_WMB     = 167772160;    // 3145728    Wm bf16 (L,T,H,H) natural
static constexpr size_t OFF_WIH     = 170917888;    // 1179648    Wih bf16
static constexpr size_t OFF_WHH     = 172097536;    // 1179648    Whh bf16
static constexpr size_t WS_REQUIRED = 173277184;    // < 175.9 MB proven safe

// ---------------- edge preprocessing: counting sort by key=(dst*8+type) ----------------
__global__ void hist_kernel(const int* __restrict__ dst, const int* __restrict__ et,
                            int* __restrict__ cnt) {
  int e = blockIdx.x * 256 + threadIdx.x;
  atomicAdd(&cnt[dst[e] * T_TYPES + et[e]], 1);
}

__global__ __launch_bounds__(1024) void scan1(const int* __restrict__ cnt,
                                              int* __restrict__ offs,
                                              int* __restrict__ bsum) {
  __shared__ int wsum[16];
  const int t = threadIdx.x, lane = t & 63, wid = t >> 6;
  const int idx = blockIdx.x * 1024 + t;
  const int v = cnt[idx];
  int x = v;
  #pragma unroll
  for (int off = 1; off < 64; off <<= 1) {
    int u = __shfl_up(x, off, 64);
    if (lane >= off) x += u;
  }
  if (lane == 63) wsum[wid] = x;
  __syncthreads();
  int wbase = 0;
  for (int i = 0; i < wid; ++i) wbase += wsum[i];
  offs[idx] = wbase + x - v;
  if (t == 1023) bsum[blockIdx.x] = wbase + x;
}

__global__ __launch_bounds__(256) void scan2(int* __restrict__ bsum) {
  __shared__ int wsum[4];
  const int t = threadIdx.x, lane = t & 63, wid = t >> 6;
  const int v = bsum[t];
  int x = v;
  #pragma unroll
  for (int off = 1; off < 64; off <<= 1) {
    int u = __shfl_up(x, off, 64);
    if (lane >= off) x += u;
  }
  if (lane == 63) wsum[wid] = x;
  __syncthreads();
  int wbase = 0;
  for (int i = 0; i < wid; ++i) wbase += wsum[i];
  __syncthreads();
  bsum[t] = wbase + x - v;
}

__global__ __launch_bounds__(1024) void scan3(int* __restrict__ offs,
                                              const int* __restrict__ bsum,
                                              int* __restrict__ cursor) {
  const int idx = blockIdx.x * 1024 + threadIdx.x;
  const int o = offs[idx] + bsum[blockIdx.x];
  offs[idx] = o;
  cursor[idx] = o;
  if (idx == 0) offs[NT_BINS] = E_EDGES;
}

__global__ void reorder_kernel(const int* __restrict__ src, const int* __restrict__ dst,
                               const int* __restrict__ et, int* __restrict__ cursor,
                               unsigned short* __restrict__ sorted) {
  int e = blockIdx.x * 256 + threadIdx.x;
  int key = dst[e] * T_TYPES + et[e];
  int p = atomicAdd(&cursor[key], 1);
  sorted[p] = (unsigned short)src[e];
}

// ---------------- conversions (G13: 8 elems/thread, vector stores) ----------
__global__ void cvt_weights8(const float* __restrict__ a, const float* __restrict__ b,
                             const float* __restrict__ c,
                             unsigned short* __restrict__ oa, unsigned short* __restrict__ ob,
                             unsigned short* __restrict__ oc,
                             int na, int nb, int nc) {
  const int i = (blockIdx.x * 256 + threadIdx.x) * 8;
  const float* s; unsigned short* d; int off;
  if (i < na) { s = a; d = oa; off = i; }
  else {
    const int j = i - na;
    if (j < nb) { s = b; d = ob; off = j; }
    else {
      const int k = j - nb;
      if (k >= nc) return;
      s = c; d = oc; off = k;
    }
  }
  // na/nb multiples of 8 -> off multiple of 8 -> 32B-aligned float4 loads
  const float4 v0 = *(const float4*)(s + off);
  const float4 v1 = *(const float4*)(s + off + 4);
  union { unsigned short us[8]; uint4 q; } o;
  o.us[0] = f2bf(v0.x); o.us[1] = f2bf(v0.y); o.us[2] = f2bf(v0.z); o.us[3] = f2bf(v0.w);
  o.us[4] = f2bf(v1.x); o.us[5] = f2bf(v1.y); o.us[6] = f2bf(v1.z); o.us[7] = f2bf(v1.w);
  *(uint4*)(d + off) = o.q;
}

__global__ void pad_cvt8(const float* __restrict__ in, unsigned short* __restrict__ out,
                         int rows, int cin) {
  const int i = (blockIdx.x * 256 + threadIdx.x) * 8;
  if (i >= rows * 256) return;
  const int r = i >> 8, c0 = i & 255;
  union { unsigned short us[8]; uint4 q; } o;
  #pragma unroll
  for (int j = 0; j < 8; ++j) {
    const int c = c0 + j;
    o.us[j] = (c < cin) ? f2bf(in[(size_t)r * cin + c]) : (unsigned short)0;
  }
  *(uint4*)(out + i) = o.q;   // i multiple of 8 shorts -> 16B aligned
}

// ---------------- GEMM: C(N x M) = A(N x K) @ W(M x K)^T + bias (input proj) ------
// 2-phase pipelined + XOR slot swizzle (unchanged, verified).
__global__ __launch_bounds__(256, 2) void gemm_bt(
    const unsigned short* __restrict__ A,
    const unsigned short* __restrict__ W,
    const float* __restrict__ bias,
    unsigned short* __restrict__ C,
    int M, int K) {
  __shared__ unsigned short As[2][128 * 32];
  __shared__ unsigned short Bs[2][128 * 32];
  const int tid = threadIdx.x;
  const int lane = tid & 63;
  const int wv = tid >> 6;
  const int lrow = lane & 15;
  const int lquad = lane >> 4;
  const int bm0 = blockIdx.x * 128;
  const int bn0 = blockIdx.y * 128;
  const int srow = wv * 16 + (lane >> 2);
  const int sslot = lane & 3;
  const int scol = sslot * 8;
  const int ssw = (sslot ^ ((lane >> 3) & 3)) * 8;   // swizzled global col
  const int rsw = (lquad ^ ((lane >> 1) & 3)) * 8;   // swizzled LDS read col

  f32x4 acc[2][8] = {};

#define GBT_STAGE(b, kt)                                                              \
  { _Pragma("unroll") for (int i = 0; i < 2; ++i) {                                   \
      const int row = srow + i * 64;                                                  \
      gload_lds16(A + (size_t)(bm0 + row) * K + (kt) + ssw, &As[b][row * 32 + scol]); \
      gload_lds16(W + (size_t)(bn0 + row) * K + (kt) + ssw, &Bs[b][row * 32 + scol]); \
    } }

  GBT_STAGE(0, 0);
  __syncthreads();
  const int nk = K >> 5;
  for (int ki = 0; ki < nk; ++ki) {
    const int cur = ki & 1;
    if (ki + 1 < nk) GBT_STAGE(cur ^ 1, (ki + 1) * 32);
    bf16x8 af[2], bfr[8];
    #pragma unroll
    for (int mt = 0; mt < 2; ++mt)
      af[mt] = *(const bf16x8*)(&As[cur][(wv * 32 + mt * 16 + lrow) * 32 + rsw]);
    #pragma unroll
    for (int nt = 0; nt < 8; ++nt)
      bfr[nt] = *(const bf16x8*)(&Bs[cur][(nt * 16 + lrow) * 32 + rsw]);
    #pragma unroll
    for (int mt = 0; mt < 2; ++mt)
      #pragma unroll
      for (int nt = 0; nt < 8; ++nt)
        acc[mt][nt] = __builtin_amdgcn_mfma_f32_16x16x32_bf16(af[mt], bfr[nt], acc[mt][nt], 0, 0, 0);
    __syncthreads();
  }
#undef GBT_STAGE

  #pragma unroll
  for (int mt = 0; mt < 2; ++mt) {
    #pragma unroll
    for (int r = 0; r < 4; ++r) {
      const int grow = bm0 + wv * 32 + mt * 16 + lquad * 4 + r;
      #pragma unroll
      for (int nt = 0; nt < 8; ++nt) {
        const int gcol = bn0 + nt * 16 + lrow;
        float v = acc[mt][nt][r] + (bias ? bias[gcol] : 0.f);
        C[(size_t)grow * M + gcol] = f2bf(v);
      }
    }
  }
}

// ---------------- fused message GEMM: counted-vmcnt phase B, 2x4 wave tiles --
// (round-10 verified 81.3us; pk-add gather r11. FROZEN.)
__global__ __launch_bounds__(512, 4) void msg_gemm(
    const int* __restrict__ offs, const unsigned short* __restrict__ sorted,
    const unsigned short* __restrict__ hb, const unsigned short* __restrict__ Wt_l,
    const float* __restrict__ bm_l, unsigned short* __restrict__ m) {
  constexpr int CH = 2568;                    // Ss chunk stride (shorts)
  __shared__ unsigned short Ss[8 * CH];       // 41.1 KB
  __shared__ unsigned short Bs[2][256 * 32];  // 32 KB ping-pong
  __shared__ unsigned short idxS[2048];       // 4 KB edge indices
  __shared__ int offsS[516];                  // 2 KB offs segment
  const int tid = threadIdx.x;
  const int lane = tid & 63;
  const int wv = tid >> 6;            // 0..7
  const int lrow = lane & 15;
  const int lquad = lane >> 4;
  const int wr2 = wv & 1;             // row half: rows wr2*32 .. +31
  const int wc4 = wv >> 1;            // col quarter: cols wc4*64 .. +63
  const int bm0 = blockIdx.x * 64;
  const int gg = wv * 4 + lquad;      // gather group 0..31
  const int brow = tid >> 2;          // 0..127 (Bs staging row)
  const int bslot = tid & 3;
  const int bcol = bslot * 8;
  const int bsw = (bslot ^ ((tid >> 3) & 3)) * 8;    // swizzled global col (stage)
  const int rsw = (lquad ^ ((lane >> 1) & 3)) * 8;   // swizzled LDS read col

#define MSG_STAGE(W_, kc_, b_)                                                         \
  { gload_lds16((W_) + (size_t)brow * 256 + (kc_) * 32 + bsw, &Bs[b_][brow * 32 + bcol]); \
    gload_lds16((W_) + (size_t)(brow + 128) * 256 + (kc_) * 32 + bsw,                  \
                &Bs[b_][(brow + 128) * 32 + bcol]); }

  // ---- stage offs + edge-index segments; prefetch (t0,kc0) weights ----
  MSG_STAGE(Wt_l, 0, 0);
  const int gseg0 = offs[bm0 * 8];
  const int gseg1 = offs[bm0 * 8 + 512];
  const int seg = gseg1 - gseg0;
  for (int i = tid; i < 513; i += 512) offsS[i] = offs[bm0 * 8 + i];
  const int segc = seg < 2048 ? seg : 2048;
  for (int i = tid; i < segc; i += 512) idxS[i] = sorted[gseg0 + i];
  const bool useLds = (seg <= 2048);
  const unsigned short* ip = useLds ? (const unsigned short*)idxS : (sorted + gseg0);
  __syncthreads();

  f32x4 acc[2][4] = {};   // [row-tile mt][col-tile nt]
  int buf = 0;

  for (int t = 0; t < T_TYPES; ++t) {
    // ---- phase A: build S_t (64 x 256) in LDS (packed-add gather) ----
    #pragma unroll
    for (int step = 0; step < 2; ++step) {
      const int dloc = gg + step * 32;
      const int beg = offsS[dloc * 8 + t] - gseg0;
      const int end = offsS[dloc * 8 + t + 1] - gseg0;
      f32x2 a[8];
      #pragma unroll
      for (int j = 0; j < 8; ++j) a[j] = (f32x2){0.f, 0.f};
      int e = beg;
      if (e + 2 <= end) {
        int s0 = ip[e], s1 = ip[e + 1];
        const unsigned short* h0 = hb + (size_t)s0 * H_DIM + lrow * 16;
        const unsigned short* h1 = hb + (size_t)s1 * H_DIM + lrow * 16;
        uint4 pv0 = *(const uint4*)h0, pw0 = *(const uint4*)(h0 + 8);
        uint4 pv1 = *(const uint4*)h1, pw1 = *(const uint4*)(h1 + 8);
        e += 2;
        for (; e + 2 <= end; e += 2) {
          const int n0 = ip[e], n1 = ip[e + 1];
          const unsigned short* g0 = hb + (size_t)n0 * H_DIM + lrow * 16;
          const unsigned short* g1 = hb + (size_t)n1 * H_DIM + lrow * 16;
          const uint4 nv0 = *(const uint4*)g0, nw0 = *(const uint4*)(g0 + 8);
          const uint4 nv1 = *(const uint4*)g1, nw1 = *(const uint4*)(g1 + 8);
          acc16p(a, pv0, pw0);
          acc16p(a, pv1, pw1);
          pv0 = nv0; pw0 = nw0; pv1 = nv1; pw1 = nw1;
        }
        acc16p(a, pv0, pw0);
        acc16p(a, pv1, pw1);
      }
      if (e < end) {
        const int s0 = ip[e];
        const unsigned short* h0 = hb + (size_t)s0 * H_DIM + lrow * 16;
        acc16p(a, *(const uint4*)h0, *(const uint4*)(h0 + 8));
      }
      union { unsigned short us[16]; uint4 q[2]; } ob;
      #pragma unroll
      for (int j = 0; j < 8; ++j) {
        ob.us[2 * j]     = f2bf(a[j][0]);
        ob.us[2 * j + 1] = f2bf(a[j][1]);
      }
      uint4* p = (uint4*)&Ss[(lrow >> 1) * CH + dloc * 40 + (lrow & 1) * 16];
      p[0] = ob.q[0];
      p[1] = ob.q[1];
    }
    __syncthreads();   // full drain: Ss ds_writes visible; Bs[buf] (kc0) drained
    const unsigned short* Wt  = Wt_l + (size_t)t * 65536;
    const unsigned short* Wtn = Wt_l + (size_t)(t + 1) * 65536;  // deref'd only t<7
    // ---- phase B: acc += S_t @ Wm[t]^T ----
    for (int kc = 0; kc < 8; ++kc) {
      if (kc < 7) {
        MSG_STAGE(Wt, kc + 1, buf ^ 1);            // prefetch kc+1
      } else if (t < 7) {
        MSG_STAGE(Wtn, 0, buf ^ 1);                // cross-type prefetch kc0
      }
      if (t == 7 && kc == 7) {
        asm volatile("s_waitcnt vmcnt(0)" ::: "memory");
      } else {
        asm volatile("s_waitcnt vmcnt(2)" ::: "memory");  // drain kc's tile only
      }
      __builtin_amdgcn_s_barrier();                // all waves' kc tile in LDS
      __builtin_amdgcn_sched_barrier(0);
      bf16x8 af[2], bfr[4];
      #pragma unroll
      for (int mt = 0; mt < 2; ++mt)
        af[mt] = *(const bf16x8*)(&Ss[kc * CH + (wr2 * 32 + mt * 16 + lrow) * 40 + lquad * 8]);
      #pragma unroll
      for (int nt = 0; nt < 4; ++nt)
        bfr[nt] = *(const bf16x8*)(&Bs[buf][((wc4 * 4 + nt) * 16 + lrow) * 32 + rsw]);
      #pragma unroll
      for (int mt = 0; mt < 2; ++mt)
        #pragma unroll
        for (int nt = 0; nt < 4; ++nt)
          acc[mt][nt] = __builtin_amdgcn_mfma_f32_16x16x32_bf16(af[mt], bfr[nt], acc[mt][nt], 0, 0, 0);
      buf ^= 1;
      __builtin_amdgcn_s_barrier();                // reads done before overwrite
      __builtin_amdgcn_sched_barrier(0);
    }
  }
#undef MSG_STAGE

  // ---- epilogue: m = acc + sum_t cnt[dst,t]*bm[t,:]; cnt from offsS deltas ----
  #pragma unroll
  for (int mt = 0; mt < 2; ++mt) {
    float cnt[4][8];
    #pragma unroll
    for (int r = 0; r < 4; ++r) {
      const int dl = wr2 * 32 + mt * 16 + lquad * 4 + r;
      #pragma unroll
      for (int t = 0; t < 8; ++t)
        cnt[r][t] = (float)(offsS[dl * 8 + t + 1] - offsS[dl * 8 + t]);
    }
    #pragma unroll
    for (int nt = 0; nt < 4; ++nt) {
      const int gcol = wc4 * 64 + nt * 16 + lrow;
      float bmv[8];
      #pragma unroll
      for (int t = 0; t < 8; ++t) bmv[t] = bm_l[t * H_DIM + gcol];
      #pragma unroll
      for (int r = 0; r < 4; ++r) {
        const int grow = bm0 + wr2 * 32 + mt * 16 + lquad * 4 + r;
        float v = acc[mt][nt][r];
        #pragma unroll
        for (int t = 0; t < 8; ++t) v += cnt[r][t] * bmv[t];
        m[(size_t)grow * H_DIM + gcol] = f2bf(v);
      }
    }
  }
}

// ---------------- fused GRU: 64-node tile, 4-accumulator gate fusion --------
// (round-12 verified: session-best total 593.1us. Algebraic AGPR reduction:
// r/z gates accumulate m@W and h@U into ONE tile each (2 chained MFMAs);
// only n keeps separate i_n/h_n. acc 6->4 tiles = 64 AGPR; single-buffer
// bfr[6] reloaded after last use (r9 pattern). ~80+24+64 regs, 3 waves/SIMD
// at (256,3) with headroom. r13's bfr dbuf (168/170 regs) was neutral-to-
// negative (605.8 vs 593.1) -> reverted. FROZEN.)
__global__ __launch_bounds__(256, 3) void gru_fused(
    const unsigned short* __restrict__ mB,
    const unsigned short* __restrict__ hin,
    const unsigned short* __restrict__ wih_l,
    const unsigned short* __restrict__ whh_l,
    const float* __restrict__ bih_l,
    const float* __restrict__ bhh_l,
    unsigned short* __restrict__ hout) {
  __shared__ unsigned short Am[2][64 * 32];   // 8 KB dbuf
  __shared__ unsigned short Ah[2][64 * 32];   // 8 KB dbuf
  const int tid = threadIdx.x;
  const int lane = tid & 63;
  const int wv = tid >> 6;
  const int lrow = lane & 15;
  const int lquad = lane >> 4;
  const int n0 = blockIdx.x * 64;
  const int c0 = blockIdx.y * 64;
  const int arow = tid >> 2;
  const int sslot = tid & 3;
  const int ssw = (sslot ^ ((tid >> 3) & 3)) * 8;    // swizzled global col (stage)
  const int rsw = (lquad ^ ((lane >> 1) & 3)) * 8;   // swizzled LDS read col
  const int wr = c0 + wv * 16 + lrow;

  // acc tiles: 0 = i_r+h_r, 1 = i_z+h_z, 2 = i_n, 3 = h_n
  f32x4 acc[4][4] = {};
  bf16x8 bfr[6];

#define GRU_LOADB(kt)                                                                          \
  { _Pragma("unroll") for (int g = 0; g < 3; ++g) {                                            \
      bfr[g]     = *(const bf16x8*)(wih_l + (size_t)(g * 256 + wr) * 256 + (kt) + lquad * 8);  \
      bfr[g + 3] = *(const bf16x8*)(whh_l + (size_t)(g * 256 + wr) * 256 + (kt) + lquad * 8);  \
    } }
#define GRU_STAGE(b, kt)                                                                       \
  { gload_lds16(mB  + (size_t)(n0 + arow) * 256 + (kt) + ssw, &Am[b][arow * 32 + sslot * 8]);  \
    gload_lds16(hin + (size_t)(n0 + arow) * 256 + (kt) + ssw, &Ah[b][arow * 32 + sslot * 8]); }

  GRU_LOADB(0);
  GRU_STAGE(0, 0);
  __syncthreads();

  #pragma unroll 1
  for (int ki = 0; ki < 8; ++ki) {
    const int cur = ki & 1;
    if (ki < 7) GRU_STAGE(cur ^ 1, (ki + 1) * 32);   // VMEM->LDS prefetch
    #pragma unroll
    for (int mt = 0; mt < 4; ++mt) {
      const bf16x8 am = *(const bf16x8*)(&Am[cur][(mt * 16 + lrow) * 32 + rsw]);
      const bf16x8 ah = *(const bf16x8*)(&Ah[cur][(mt * 16 + lrow) * 32 + rsw]);
      // r-gate sum: m@W_ir + h@W_hr into one tile
      acc[0][mt] = __builtin_amdgcn_mfma_f32_16x16x32_bf16(am, bfr[0], acc[0][mt], 0, 0, 0);
      acc[0][mt] = __builtin_amdgcn_mfma_f32_16x16x32_bf16(ah, bfr[3], acc[0][mt], 0, 0, 0);
      // z-gate sum
      acc[1][mt] = __builtin_amdgcn_mfma_f32_16x16x32_bf16(am, bfr[1], acc[1][mt], 0, 0, 0);
      acc[1][mt] = __builtin_amdgcn_mfma_f32_16x16x32_bf16(ah, bfr[4], acc[1][mt], 0, 0, 0);
      // n-gate halves (kept separate for r * h_n)
      acc[2][mt] = __builtin_amdgcn_mfma_f32_16x16x32_bf16(am, bfr[2], acc[2][mt], 0, 0, 0);
      acc[3][mt] = __builtin_amdgcn_mfma_f32_16x16x32_bf16(ah, bfr[5], acc[3][mt], 0, 0, 0);
    }
    if (ki < 7) GRU_LOADB((ki + 1) * 32);   // reload bfr after last use
    __syncthreads();   // drains prefetch + bfr loads; protects dbuf reuse
  }
#undef GRU_LOADB
#undef GRU_STAGE

  const int c = c0 + wv * 16 + lrow;
  const float b_ir = bih_l[c], b_iz = bih_l[256 + c], b_in = bih_l[512 + c];
  const float b_hr = bhh_l[c], b_hz = bhh_l[256 + c], b_hn = bhh_l[512 + c];
  #pragma unroll
  for (int mt = 0; mt < 4; ++mt) {
    #pragma unroll
    for (int r = 0; r < 4; ++r) {
      const int node = n0 + mt * 16 + lquad * 4 + r;
      const float s_r = acc[0][mt][r] + b_ir + b_hr;   // i_r + h_r (+biases)
      const float s_z = acc[1][mt][r] + b_iz + b_hz;
      const float i_n = acc[2][mt][r] + b_in;
      const float h_n = acc[3][mt][r] + b_hn;
      const float rr = 1.f / (1.f + __expf(-s_r));
      const float zz = 1.f / (1.f + __expf(-s_z));
      const float nn = tanhf(i_n + rr * h_n);
      const float hp = bf2f(hin[(size_t)node * 256 + c]);
      hout[(size_t)node * 256 + c] = f2bf((1.f - zz) * nn + zz * hp);
    }
  }
}

// ---------------- readout ----------------
__global__ __launch_bounds__(256) void readout_partial(const unsigned short* __restrict__ hb,
                                                       float* __restrict__ part) {
  const int b = blockIdx.x >> 3;
  const int ch = blockIdx.x & 7;
  const int c = threadIdx.x;
  const unsigned short* base = hb + ((size_t)b * MAXN_ + ch * 128) * H_DIM + c;
  float s = 0.f;
  #pragma unroll 4
  for (int i = 0; i < 128; ++i) s += bf2f(base[(size_t)i * H_DIM]);
  part[(size_t)blockIdx.x * H_DIM + c] = s;
}

__global__ __launch_bounds__(256) void readout_final(const float* __restrict__ part,
                                                     float* __restrict__ out) {
  const int b = blockIdx.x;
  const int c = threadIdx.x;
  float s = 0.f;
  #pragma unroll
  for (int i = 0; i < 8; ++i) s += part[((size_t)b * 8 + i) * H_DIM + c];
  out[b * H_DIM + c] = s;
}

// ---------------- launch ----------------
extern "C" void kernel_launch(void* const* d_in, const int* in_sizes, int n_in,
                              void* d_out, int out_size, void* d_ws, size_t ws_size,
                              hipStream_t stream) {
  if (ws_size < WS_REQUIRED) return;  // diagnostic no-op guard

  const float* X   = (const float*)d_in[0];
  const int*   ei  = (const int*)d_in[1];
  const int*   et  = (const int*)d_in[2];
  const float* Wp  = (const float*)d_in[3];
  const float* bp  = (const float*)d_in[4];
  const float* Wm  = (const float*)d_in[5];
  const float* bm  = (const float*)d_in[6];
  const float* Wih = (const float*)d_in[7];
  const float* Whh = (const float*)d_in[8];
  const float* bih = (const float*)d_in[9];
  const float* bhh = (const float*)d_in[10];
  float* out = (float*)d_out;
  char* ws = (char*)d_ws;

  // BIG aliases (stream-ordered liveness)
  int*            counts = (int*)(ws + OFF_BIG);
  int*            cursor = (int*)(ws + OFF_BIG + REL_CURSOR);
  int*            bsum   = (int*)(ws + OFF_BIG + REL_BSUM);
  unsigned short* xpad   = (unsigned short*)(ws + OFF_BIG);
  unsigned short* wppad  = (unsigned short*)(ws + OFF_BIG + REL_WPPAD);
  unsigned short* h_alt  = (unsigned short*)(ws + OFF_BIG + REL_HALT);
  float*          part   = (float*)(ws + OFF_BIG);
  int*            offs   = (int*)(ws + OFF_BIG + REL_OFFS);
  unsigned short* sorted = (unsigned short*)(ws + OFF_BIG + REL_SORTED);
  // persistent
  unsigned short* h_b    = (unsigned short*)(ws + OFF_H_B);
  unsigned short* m_b    = (unsigned short*)(ws + OFF_M_B);
  unsigned short* wmb    = (unsigned short*)(ws + OFF_WMB);
  unsigned short* wih_b  = (unsigned short*)(ws + OFF_WIH);
  unsigned short* whh_b  = (unsigned short*)(ws + OFF_WHH);

  const int* src = ei;
  const int* dst = ei + E_EDGES;

  // ---- counting sort of edges by (dst*8 + type), once ----
  hipMemsetAsync(counts, 0, NT_BINS * sizeof(int), stream);
  hist_kernel<<<E_EDGES / 256, 256, 0, stream>>>(dst, et, counts);
  scan1<<<NT_BINS / 1024, 1024, 0, stream>>>(counts, offs, bsum);
  scan2<<<1, 256, 0, stream>>>(bsum);
  scan3<<<NT_BINS / 1024, 1024, 0, stream>>>(offs, bsum, cursor);
  reorder_kernel<<<E_EDGES / 256, 256, 0, stream>>>(src, dst, et, cursor, sorted);

  // ---- weight/input conversion to bf16 (vectorized 8/thread) ----
  pad_cvt8<<<(N_NODES * 256) / 2048, 256, 0, stream>>>(X, xpad, N_NODES, F_IN);
  pad_cvt8<<<(256 * 256) / 2048, 256, 0, stream>>>(Wp, wppad, 256, F_IN);
  {
    const int na = L_LAYERS * T_TYPES * H_DIM * H_DIM;   // 1572864
    const int nb = L_LAYERS * 3 * H_DIM * H_DIM;         // 589824
    const int nc = nb;
    cvt_weights8<<<((na + nb + nc) / 8 + 255) / 256, 256, 0, stream>>>(
        Wm, Wih, Whh, wmb, wih_b, whh_b, na, nb, nc);
  }

  // ---- input projection: h = X @ Wp^T + bp ----
  gemm_bt<<<dim3(N_NODES / 128, 2), 256, 0, stream>>>(xpad, wppad, bp, h_b, H_DIM, 256);

  for (int l = 0; l < L_LAYERS; ++l) {
    const unsigned short* wm_l  = wmb + (size_t)l * T_TYPES * H_DIM * H_DIM;
    const unsigned short* wih_l = wih_b + (size_t)l * 3 * H_DIM * H_DIM;
    const unsigned short* whh_l = whh_b + (size_t)l * 3 * H_DIM * H_DIM;
    const float* bm_l  = bm + (size_t)l * T_TYPES * H_DIM;
    const float* bih_l = bih + (size_t)l * 3 * H_DIM;
    const float* bhh_l = bhh + (size_t)l * 3 * H_DIM;

    unsigned short* h_cur = (l & 1) ? h_alt : h_b;
    unsigned short* h_nxt = (l & 1) ? h_b : h_alt;

    // fused: m = (scatter-sum_t h) @ Wm^T + cnt-weighted bm  (S stays in LDS)
    msg_gemm<<<N_NODES / 64, 512, 0, stream>>>(offs, sorted, h_cur, wm_l, bm_l, m_b);
    // fused: h_nxt = GRU(m, h_cur)  (gi/gh stay in registers)
    gru_fused<<<dim3(N_NODES / 64, 4), 256, 0, stream>>>(
        m_b, h_cur, wih_l, whh_l, bih_l, bhh_l, h_nxt);
  }

  // final h is in h_alt (l=2 writes h_alt); part at BIG+0 is disjoint
  readout_partial<<<B_GRAPHS * 8, 256, 0, stream>>>(h_alt, part);
  readout_final<<<B_GRAPHS, 256, 0, stream>>>(part, out);

  (void)in_sizes; (void)n_in; (void)out_size;
}